// Round 4
// baseline (1185.302 us; speedup 1.0000x reference)
//
#include <hip/hip_runtime.h>
#include <math.h>

#define T_LEN   2048
#define NKH     16
#define NVH     32
#define HD      64
#define KEY_DIM 1024
#define VAL_DIM 2048
#define CONV_DIM 4096
#define NCHUNK  32
#define CL      64

typedef float fl4 __attribute__((ext_vector_type(4)));

__device__ __forceinline__ float sigmoid_f(float x) { return 1.f / (1.f + __expf(-x)); }

// ---------------------------------------------------------------------------
// Kernel 1: causal conv1d (W=4) + silu + head split + qk l2norm + gates.
// v output is pre-scaled by beta (the only consumer of v is beta*v).
// ---------------------------------------------------------------------------
__global__ __launch_bounds__(256) void prep_kernel(
    const float* __restrict__ x,        // [T, 4096]
    const float* __restrict__ cs,       // [3, 4096]
    const float* __restrict__ w,        // [4096, 4]
    const float* __restrict__ bsrc,     // [T, 32]
    const float* __restrict__ a,        // [T, 32]
    const float* __restrict__ A_log,    // [32]
    const float* __restrict__ dt_bias,  // [32]
    float* __restrict__ qn,             // [T, 16, 64]
    float* __restrict__ kn,             // [T, 16, 64]
    float* __restrict__ vb,             // [T, 32, 64]  beta*v
    float* __restrict__ g,              // [T, 32]
    float* __restrict__ beta)           // [T, 32]
{
    const int t   = blockIdx.x;
    const int tid = threadIdx.x;
    const int d0  = tid * 16;

    fl4 r4[4];
    #pragma unroll
    for (int grp = 0; grp < 4; ++grp) {
        const int d = d0 + grp * 4;
        fl4 xv[4], wq[4];
        #pragma unroll
        for (int wi = 0; wi < 4; ++wi) {
            const int row = t - 3 + wi;
            const float* src = (row >= 0) ? (x + (size_t)row * CONV_DIM + d)
                                          : (cs + (size_t)(row + 3) * CONV_DIM + d);
            xv[wi] = *(const fl4*)src;
        }
        #pragma unroll
        for (int j = 0; j < 4; ++j) wq[j] = *(const fl4*)(w + (size_t)(d + j) * 4);
        #pragma unroll
        for (int j = 0; j < 4; ++j) {
            float acc = xv[0][j] * wq[j][0];
            acc = fmaf(xv[1][j], wq[j][1], acc);
            acc = fmaf(xv[2][j], wq[j][2], acc);
            acc = fmaf(xv[3][j], wq[j][3], acc);
            r4[grp][j] = acc * sigmoid_f(acc);
        }
    }

    if (tid < 128) {
        float ss = 0.f;
        #pragma unroll
        for (int grp = 0; grp < 4; ++grp)
            #pragma unroll
            for (int j = 0; j < 4; ++j) ss = fmaf(r4[grp][j], r4[grp][j], ss);
        ss += __shfl_xor(ss, 1);
        ss += __shfl_xor(ss, 2);
        const bool is_q = (tid < 64);
        float scale = (is_q ? 0.125f : 1.0f) / sqrtf(ss + 1e-6f);
        float* dst = is_q ? (qn + (size_t)t * KEY_DIM + d0)
                          : (kn + (size_t)t * KEY_DIM + (d0 - KEY_DIM));
        #pragma unroll
        for (int grp = 0; grp < 4; ++grp) {
            fl4 o;
            #pragma unroll
            for (int j = 0; j < 4; ++j) o[j] = r4[grp][j] * scale;
            *(fl4*)(dst + grp * 4) = o;
        }
    } else {
        const int hh = (d0 - 2 * KEY_DIM) >> 6;
        const float bb = sigmoid_f(bsrc[(size_t)t * NVH + hh]);
        float* dst = vb + (size_t)t * VAL_DIM + (d0 - 2 * KEY_DIM);
        #pragma unroll
        for (int grp = 0; grp < 4; ++grp) {
            fl4 o;
            #pragma unroll
            for (int j = 0; j < 4; ++j) o[j] = r4[grp][j] * bb;
            *(fl4*)(dst + grp * 4) = o;
        }
    }

    if (tid < 32) {
        float av = a[(size_t)t * NVH + tid] + dt_bias[tid];
        float sp = fmaxf(av, 0.f) + log1pf(__expf(-fabsf(av)));
        g[(size_t)t * NVH + tid]    = -__expf(A_log[tid]) * sp;
        beta[(size_t)t * NVH + tid] = sigmoid_f(bsrc[(size_t)t * NVH + tid]);
    }
}

// ---------------------------------------------------------------------------
// Kernel 2 (phase 1): per (chunk c, v-head h), fully parallel.
// LDS trimmed to 4 tiles (M written in-place over Qs) -> 2 blocks/CU.
// ---------------------------------------------------------------------------
__global__ __launch_bounds__(256) void phase1_kernel(
    const float* __restrict__ qn, const float* __restrict__ kn,
    const float* __restrict__ gws, const float* __restrict__ bws,
    float* __restrict__ gam_g, float* __restrict__ bg_g,
    float* __restrict__ KT_g, float* __restrict__ QT_g,
    float* __restrict__ MTt_g, float* __restrict__ SUt_g)
{
    const int bid = blockIdx.x;
    const int c = bid >> 5, h = bid & 31, kh = h >> 1;
    const int tid = threadIdx.x, lane = tid & 63, wv = tid >> 6;

    __shared__ float Ks[64][68], Qs[64][68], Am[64][68], Tm[64][68];
    __shared__ float Gs[64], Dend[64], Bet[64];
    __shared__ float Xs[4][16][17];

    // load K,Q tiles
    #pragma unroll
    for (int p = 0; p < 4; ++p) {
        int idx = p * 256 + tid;
        int t = idx >> 4, i4 = (idx & 15) * 4;
        *(fl4*)&Ks[t][i4] = *(const fl4*)&kn[(size_t)(c*64+t)*KEY_DIM + kh*64 + i4];
        *(fl4*)&Qs[t][i4] = *(const fl4*)&qn[(size_t)(c*64+t)*KEY_DIM + kh*64 + i4];
    }
    // Tm = I
    for (int idx = tid; idx < 64*64; idx += 256) {
        int t = idx >> 6, s = idx & 63;
        Tm[t][s] = (t == s) ? 1.f : 0.f;
    }
    // gates: wave 0 cumsum via shfl_up
    if (tid < 64) {
        float gv = gws[(size_t)(c*64+lane)*NVH + h];
        #pragma unroll
        for (int d = 1; d < 64; d <<= 1) {
            float nv = __shfl_up(gv, d);
            if (lane >= d) gv += nv;
        }
        Gs[lane] = gv;
        float g63 = __shfl(gv, 63);
        Dend[lane] = __expf(g63 - gv);
        float bb = bws[(size_t)(c*64+lane)*NVH + h];
        Bet[lane] = bb;
        float ga = __expf(gv);
        gam_g[(size_t)(c*NVH+h)*64 + lane] = ga;
        bg_g[(size_t)(c*NVH+h)*64 + lane]  = ga * bb;
    }
    __syncthreads();

    // packed transposes (before Qs gets overwritten by M); once per k-head
    if ((h & 1) == 0) {
        float* kdst = KT_g + (size_t)(c*NKH + kh)*64*64;
        float* qdst = QT_g + (size_t)(c*NKH + kh)*64*64;
        const int t = lane;
        #pragma unroll
        for (int ii = 0; ii < 16; ++ii) {
            int i = wv*16 + ii;
            kdst[i*64 + t] = Ks[t][i];
            qdst[i*64 + t] = Qs[t][i];
        }
    }

    // A = beta*exp(dG)*K K^T (strict lower), M = exp(dG)*Q K^T (incl lower)
    float accK[16], accQ[16];
    {
        #pragma unroll
        for (int j = 0; j < 16; ++j) { accK[j] = 0.f; accQ[j] = 0.f; }
        const int t = lane, sbase = wv * 16;
        for (int i4 = 0; i4 < 64; i4 += 4) {
            fl4 kt = *(const fl4*)&Ks[t][i4];
            fl4 qt = *(const fl4*)&Qs[t][i4];
            #pragma unroll
            for (int sj = 0; sj < 16; ++sj) {
                fl4 ks = *(const fl4*)&Ks[sbase + sj][i4];   // broadcast
                accK[sj] += kt[0]*ks[0] + kt[1]*ks[1] + kt[2]*ks[2] + kt[3]*ks[3];
                accQ[sj] += qt[0]*ks[0] + qt[1]*ks[1] + qt[2]*ks[2] + qt[3]*ks[3];
            }
        }
    }
    __syncthreads();   // all Qs reads complete before in-place M write
    {
        const int t = lane, sbase = wv * 16;
        const float gt = Gs[t], bt = Bet[t];
        #pragma unroll
        for (int sj = 0; sj < 16; ++sj) {
            int s = sbase + sj;
            float e = __expf(gt - Gs[s]);
            Am[t][s] = (s < t)  ? bt * e * accK[sj] : 0.f;
            Qs[t][s] = (s <= t) ? e * accQ[sj] : 0.f;   // M in-place
        }
    }
    __syncthreads();

    // T = (I+A)^{-1}: diagonal 16x16 blocks by forward substitution
    if (lane < 16) {
        const int base = wv * 16;
        const int sj = lane, s = base + sj;
        for (int tl = 1; tl < 16; ++tl) {
            int t = base + tl;
            if (sj < tl) {
                float acc = 0.f;
                for (int il = sj; il < tl; ++il)
                    acc += Am[t][base + il] * Tm[base + il][s];
                Tm[t][s] = -acc;
            }
        }
    }
    // off-diagonal blocks level by level
    for (int L = 1; L <= 3; ++L) {
        __syncthreads();
        if (wv < 4 - L) {
            const int J = wv, I = wv + L;
            const int r = lane & 15, cg = lane >> 4;
            float X[4] = {0.f,0.f,0.f,0.f};
            for (int Kb = J; Kb < I; ++Kb) {
                #pragma unroll
                for (int p = 0; p < 16; ++p) {
                    float av = Am[I*16 + r][Kb*16 + p];
                    #pragma unroll
                    for (int mm = 0; mm < 4; ++mm)
                        X[mm] += av * Tm[Kb*16 + p][J*16 + cg + 4*mm];
                }
            }
            #pragma unroll
            for (int mm = 0; mm < 4; ++mm) Xs[wv][r][cg + 4*mm] = X[mm];
            float Y[4] = {0.f,0.f,0.f,0.f};
            #pragma unroll
            for (int p = 0; p < 16; ++p) {
                float td = Tm[I*16 + r][I*16 + p];
                #pragma unroll
                for (int mm = 0; mm < 4; ++mm)
                    Y[mm] += td * Xs[wv][p][cg + 4*mm];
            }
            #pragma unroll
            for (int mm = 0; mm < 4; ++mm)
                Tm[I*16 + r][J*16 + cg + 4*mm] = -Y[mm];
        }
    }
    __syncthreads();

    // MTt[s][t] = (M * T)[t][s]   (M lives in Qs)
    {
        float acc[16];
        #pragma unroll
        for (int j = 0; j < 16; ++j) acc[j] = 0.f;
        const int t = lane, sbase = wv * 16;
        for (int i4 = 0; i4 < 64; i4 += 4) {
            fl4 mv = *(const fl4*)&Qs[t][i4];
            #pragma unroll
            for (int sj = 0; sj < 16; ++sj) {
                int s = sbase + sj;
                acc[sj] += mv[0]*Tm[i4+0][s] + mv[1]*Tm[i4+1][s]
                         + mv[2]*Tm[i4+2][s] + mv[3]*Tm[i4+3][s];
            }
        }
        float* dst = MTt_g + (size_t)(c*NVH + h)*64*64;
        #pragma unroll
        for (int sj = 0; sj < 16; ++sj)
            dst[(sbase + sj)*64 + t] = acc[sj];
    }
    // SUt[s][d] = sum_t Dend[t]*K[t][d]*Tm[t][s]
    {
        float acc[16];
        #pragma unroll
        for (int j = 0; j < 16; ++j) acc[j] = 0.f;
        const int d = lane, sbase = wv * 16;
        for (int t = 0; t < 64; ++t) {
            float kd = Ks[t][d] * Dend[t];
            #pragma unroll
            for (int sj = 0; sj < 16; ++sj)
                acc[sj] += kd * Tm[t][sbase + sj];
        }
        float* dst = SUt_g + (size_t)(c*NVH + h)*64*64;
        #pragma unroll
        for (int sj = 0; sj < 16; ++sj)
            dst[(sbase + sj)*64 + d] = acc[sj];
    }
}

// ---------------------------------------------------------------------------
// Kernel 3 (phase 2): sequential over 32 chunks; block = (head, 8-col slice).
// Decode: h = bid&31, jg = bid>>5 (BIJECTIVE; R3's decode dropped bit 5).
// All 8 jg-blocks of head h have bid%8 == h%8 -> same XCD under round-robin
// dispatch, sharing the head's matrices in one L2.
// ---------------------------------------------------------------------------
__global__ __launch_bounds__(256) void phase2_kernel(
    const float* __restrict__ vb, const float* __restrict__ gam_g,
    const float* __restrict__ bg_g, const float* __restrict__ KT_g,
    const float* __restrict__ QT_g, const float* __restrict__ MTt_g,
    const float* __restrict__ SUt_g, const float* __restrict__ rs0,
    float* __restrict__ out)
{
    const int bid = blockIdx.x;
    const int h  = bid & 31;
    const int jg = bid >> 5;
    const int kh = h >> 1;
    const int tid = threadIdx.x, lane = tid & 63, wv = tid >> 6;
    const int half = wv & 1;
    const bool isPO = (wv < 2);              // waves 0,1: P then o; 2,3: O1 then s'
    const int t0 = half * 32 + (lane & 7) * 4;
    const int jj = lane >> 3;

    __shared__ float s0[64][9], wsh[64][9], o1s[64][9];

    #pragma unroll
    for (int u = 0; u < 2; ++u) {
        int idx = tid * 2 + u;
        int d = idx >> 3, j = idx & 7;
        s0[d][j] = rs0[((size_t)h*64 + d)*64 + jg*8 + j];
    }
    __syncthreads();

    for (int c = 0; c < NCHUNK; ++c) {
        const float* gamc = gam_g + (size_t)(c*NVH + h)*64;
        const float* bgc  = bg_g  + (size_t)(c*NVH + h)*64;
        const float* MxA = isPO ? (KT_g + (size_t)(c*NKH+kh)*4096)
                                : (QT_g + (size_t)(c*NKH+kh)*4096);

        // independent-of-s0 scalars: issue early
        float gv0, gv1, gv2, gv3;
        if (isPO) { gv0 = bgc[t0];  gv1 = bgc[t0+1];  gv2 = bgc[t0+2];  gv3 = bgc[t0+3]; }
        else      { gv0 = gamc[t0]; gv1 = gamc[t0+1]; gv2 = gamc[t0+2]; gv3 = gamc[t0+3]; }
        float vb0 = 0.f, vb1 = 0.f, vb2 = 0.f, vb3 = 0.f;
        if (isPO) {
            const float* vp = vb + (size_t)(c*64 + t0)*VAL_DIM + h*64 + jg*8 + jj;
            vb0 = vp[0*VAL_DIM]; vb1 = vp[1*VAL_DIM];
            vb2 = vp[2*VAL_DIM]; vb3 = vp[3*VAL_DIM];
        }
        const float gend = gamc[63];

        // Phase A: P (waves 0,1) / O1 (waves 2,3), full 64-deep
        float p0 = 0.f, p1 = 0.f, p2 = 0.f, p3 = 0.f;
        for (int ib = 0; ib < 64; ib += 16) {
            #pragma unroll
            for (int u = 0; u < 16; ++u) {
                const int i = ib + u;
                fl4 m = *(const fl4*)&MxA[i*64 + t0];
                float sv = s0[i][jj];
                p0 = fmaf(m[0], sv, p0); p1 = fmaf(m[1], sv, p1);
                p2 = fmaf(m[2], sv, p2); p3 = fmaf(m[3], sv, p3);
            }
        }
        if (isPO) {
            wsh[t0+0][jj] = vb0 - gv0*p0;
            wsh[t0+1][jj] = vb1 - gv1*p1;
            wsh[t0+2][jj] = vb2 - gv2*p2;
            wsh[t0+3][jj] = vb3 - gv3*p3;
        } else {
            o1s[t0+0][jj] = gv0*p0;
            o1s[t0+1][jj] = gv1*p1;
            o1s[t0+2][jj] = gv2*p2;
            o1s[t0+3][jj] = gv3*p3;
        }
        __syncthreads();

        // Phase B: o (waves 0,1) / state update (waves 2,3)
        const float* MxB = isPO ? (MTt_g + (size_t)(c*NVH+h)*4096)
                                : (SUt_g + (size_t)(c*NVH+h)*4096);
        float q0 = 0.f, q1 = 0.f, q2 = 0.f, q3 = 0.f;
        for (int ib = 0; ib < 64; ib += 16) {
            #pragma unroll
            for (int u = 0; u < 16; ++u) {
                const int i = ib + u;
                fl4 m = *(const fl4*)&MxB[i*64 + t0];
                float wv_ = wsh[i][jj];
                q0 = fmaf(m[0], wv_, q0); q1 = fmaf(m[1], wv_, q1);
                q2 = fmaf(m[2], wv_, q2); q3 = fmaf(m[3], wv_, q3);
            }
        }
        if (isPO) {
            float* op = out + (size_t)(c*64 + t0)*VAL_DIM + h*64 + jg*8 + jj;
            op[0*VAL_DIM] = o1s[t0+0][jj] + q0;
            op[1*VAL_DIM] = o1s[t0+1][jj] + q1;
            op[2*VAL_DIM] = o1s[t0+2][jj] + q2;
            op[3*VAL_DIM] = o1s[t0+3][jj] + q3;
        } else {
            s0[t0+0][jj] = gend*s0[t0+0][jj] + q0;
            s0[t0+1][jj] = gend*s0[t0+1][jj] + q1;
            s0[t0+2][jj] = gend*s0[t0+2][jj] + q2;
            s0[t0+3][jj] = gend*s0[t0+3][jj] + q3;
        }
        __syncthreads();
    }
}

// ---------------------------------------------------------------------------
// Fallback: sequential scan (only if ws too small). Uses vb (=beta*v).
// ---------------------------------------------------------------------------
#define LOADSTEP(KA, QA, VV, GG, BB, tt) {                                     \
    _Pragma("unroll")                                                          \
    for (int i = 0; i < 4; ++i) {                                              \
        KA[i] = *(const fl4*)(kp + (size_t)(tt) * KEY_DIM + i * 4);            \
        QA[i] = *(const fl4*)(qp + (size_t)(tt) * KEY_DIM + i * 4);            \
    }                                                                          \
    VV = vp[(size_t)(tt) * VAL_DIM];                                           \
    GG = gp[(size_t)(tt) * NVH];                                               \
    BB = bp[(size_t)(tt) * NVH];                                               \
}

#define COMPUTE(KA, QA, VV, GG, BB, tt) {                                      \
    const float dec = __expf(GG);                                              \
    float c0 = 0.f, c1 = 0.f, c2 = 0.f, c3 = 0.f;                              \
    _Pragma("unroll")                                                          \
    for (int i = 0; i < 4; ++i) {                                              \
        S[i*4+0] *= dec; S[i*4+1] *= dec; S[i*4+2] *= dec; S[i*4+3] *= dec;    \
        c0 = fmaf(S[i*4+0], KA[i][0], c0);                                     \
        c1 = fmaf(S[i*4+1], KA[i][1], c1);                                     \
        c2 = fmaf(S[i*4+2], KA[i][2], c2);                                     \
        c3 = fmaf(S[i*4+3], KA[i][3], c3);                                     \
    }                                                                          \
    float kv = (c0 + c1) + (c2 + c3);                                          \
    kv += __shfl_xor(kv, 1);                                                   \
    kv += __shfl_xor(kv, 2);                                                   \
    const float u = VV - BB * kv;                                              \
    float o0 = 0.f, o1 = 0.f, o2 = 0.f, o3 = 0.f;                              \
    _Pragma("unroll")                                                          \
    for (int i = 0; i < 4; ++i) {                                              \
        S[i*4+0] = fmaf(KA[i][0], u, S[i*4+0]);                                \
        S[i*4+1] = fmaf(KA[i][1], u, S[i*4+1]);                                \
        S[i*4+2] = fmaf(KA[i][2], u, S[i*4+2]);                                \
        S[i*4+3] = fmaf(KA[i][3], u, S[i*4+3]);                                \
        o0 = fmaf(S[i*4+0], QA[i][0], o0);                                     \
        o1 = fmaf(S[i*4+1], QA[i][1], o1);                                     \
        o2 = fmaf(S[i*4+2], QA[i][2], o2);                                     \
        o3 = fmaf(S[i*4+3], QA[i][3], o3);                                     \
    }                                                                          \
    float oo = (o0 + o1) + (o2 + o3);                                          \
    oo += __shfl_xor(oo, 1);                                                   \
    oo += __shfl_xor(oo, 2);                                                   \
    if (kg == 0) op[(size_t)(tt) * VAL_DIM] = oo;                              \
}

__global__ __launch_bounds__(256) void scan_kernel(
    const float* __restrict__ qn, const float* __restrict__ kn,
    const float* __restrict__ v, const float* __restrict__ g,
    const float* __restrict__ bet, const float* __restrict__ rs0,
    float* __restrict__ out)
{
    const int h    = blockIdx.x;
    const int kh   = h >> 1;
    const int tid  = threadIdx.x;
    const int vcol = tid >> 2;
    const int kg   = tid & 3;

    float S[16];
    #pragma unroll
    for (int j = 0; j < 16; ++j)
        S[j] = rs0[((size_t)h * HD + (kg * 16 + j)) * HD + vcol];

    const float* kp = kn + (size_t)kh * HD + kg * 16;
    const float* qp = qn + (size_t)kh * HD + kg * 16;
    const float* vp = v + (size_t)h * HD + vcol;
    const float* gp = g + h;
    const float* bp = bet + h;
    float*       op = out + (size_t)h * HD + vcol;

    fl4 ka0[4], qa0[4]; float vv0, gg0, bb0;
    fl4 ka1[4], qa1[4]; float vv1, gg1, bb1;

    LOADSTEP(ka0, qa0, vv0, gg0, bb0, 0);
    for (int t = 0; t < T_LEN; t += 2) {
        LOADSTEP(ka1, qa1, vv1, gg1, bb1, t + 1);
        COMPUTE(ka0, qa0, vv0, gg0, bb0, t);
        const int t2 = (t + 2 < T_LEN) ? (t + 2) : (T_LEN - 1);
        LOADSTEP(ka0, qa0, vv0, gg0, bb0, t2);
        COMPUTE(ka1, qa1, vv1, gg1, bb1, t + 1);
    }
}

// ---------------------------------------------------------------------------
extern "C" void kernel_launch(void* const* d_in, const int* in_sizes, int n_in,
                              void* d_out, int out_size, void* d_ws, size_t ws_size,
                              hipStream_t stream)
{
    const float* x       = (const float*)d_in[0];
    const float* cs      = (const float*)d_in[1];
    const float* rs0     = (const float*)d_in[2];
    const float* b       = (const float*)d_in[3];
    const float* a       = (const float*)d_in[4];
    const float* w       = (const float*)d_in[5];
    const float* A_log   = (const float*)d_in[6];
    const float* dt_bias = (const float*)d_in[7];
    float* out = (float*)d_out;

    float* ws = (float*)d_ws;
    size_t off = 0;
    float* qn  = ws + off; off += (size_t)T_LEN * KEY_DIM;
    float* kn  = ws + off; off += (size_t)T_LEN * KEY_DIM;
    float* vb  = ws + off; off += (size_t)T_LEN * VAL_DIM;
    float* g   = ws + off; off += (size_t)T_LEN * NVH;
    float* be  = ws + off; off += (size_t)T_LEN * NVH;
    float* gam = ws + off; off += (size_t)NCHUNK * NVH * 64;
    float* bg  = ws + off; off += (size_t)NCHUNK * NVH * 64;
    float* KT  = ws + off; off += (size_t)NCHUNK * NKH * 64 * 64;
    float* QT  = ws + off; off += (size_t)NCHUNK * NKH * 64 * 64;
    float* MTt = ws + off; off += (size_t)NCHUNK * NVH * 64 * 64;
    float* SUt = ws + off; off += (size_t)NCHUNK * NVH * 64 * 64;
    const size_t need = off * sizeof(float);

    prep_kernel<<<T_LEN, 256, 0, stream>>>(x, cs, w, b, a, A_log, dt_bias,
                                           qn, kn, vb, g, be);
    if (ws_size >= need) {
        phase1_kernel<<<NCHUNK * NVH, 256, 0, stream>>>(qn, kn, g, be,
                                                        gam, bg, KT, QT, MTt, SUt);
        phase2_kernel<<<NVH * 8, 256, 0, stream>>>(vb, gam, bg, KT, QT, MTt, SUt,
                                                   rs0, out);
    } else {
        scan_kernel<<<NVH, 256, 0, stream>>>(qn, kn, vb, g, be, rs0, out);
    }
}

// Round 5
// 304.154 us; speedup vs baseline: 3.8971x; 3.8971x over previous
//
#include <hip/hip_runtime.h>
#include <math.h>

#define T_LEN   2048
#define NKH     16
#define NVH     32
#define HD      64
#define KEY_DIM 1024
#define VAL_DIM 2048
#define CONV_DIM 4096
#define NCHUNK  32
#define CL      64

typedef float fl4 __attribute__((ext_vector_type(4)));

__device__ __forceinline__ float sigmoid_f(float x) { return 1.f / (1.f + __expf(-x)); }
__device__ __forceinline__ float rdlane(float v, int i) {
    return __int_as_float(__builtin_amdgcn_readlane(__float_as_int(v), i));
}

// ---------------------------------------------------------------------------
// Kernel 1: causal conv1d (W=4) + silu + head split + qk l2norm + gates.
// v output is pre-scaled by beta (the only consumer of v is beta*v).
// ---------------------------------------------------------------------------
__global__ __launch_bounds__(256) void prep_kernel(
    const float* __restrict__ x,        // [T, 4096]
    const float* __restrict__ cs,       // [3, 4096]
    const float* __restrict__ w,        // [4096, 4]
    const float* __restrict__ bsrc,     // [T, 32]
    const float* __restrict__ a,        // [T, 32]
    const float* __restrict__ A_log,    // [32]
    const float* __restrict__ dt_bias,  // [32]
    float* __restrict__ qn,             // [T, 16, 64]
    float* __restrict__ kn,             // [T, 16, 64]
    float* __restrict__ vb,             // [T, 32, 64]  beta*v
    float* __restrict__ g,              // [T, 32]
    float* __restrict__ beta)           // [T, 32]
{
    const int t   = blockIdx.x;
    const int tid = threadIdx.x;
    const int d0  = tid * 16;

    fl4 r4[4];
    #pragma unroll
    for (int grp = 0; grp < 4; ++grp) {
        const int d = d0 + grp * 4;
        fl4 xv[4], wq[4];
        #pragma unroll
        for (int wi = 0; wi < 4; ++wi) {
            const int row = t - 3 + wi;
            const float* src = (row >= 0) ? (x + (size_t)row * CONV_DIM + d)
                                          : (cs + (size_t)(row + 3) * CONV_DIM + d);
            xv[wi] = *(const fl4*)src;
        }
        #pragma unroll
        for (int j = 0; j < 4; ++j) wq[j] = *(const fl4*)(w + (size_t)(d + j) * 4);
        #pragma unroll
        for (int j = 0; j < 4; ++j) {
            float acc = xv[0][j] * wq[j][0];
            acc = fmaf(xv[1][j], wq[j][1], acc);
            acc = fmaf(xv[2][j], wq[j][2], acc);
            acc = fmaf(xv[3][j], wq[j][3], acc);
            r4[grp][j] = acc * sigmoid_f(acc);
        }
    }

    if (tid < 128) {
        float ss = 0.f;
        #pragma unroll
        for (int grp = 0; grp < 4; ++grp)
            #pragma unroll
            for (int j = 0; j < 4; ++j) ss = fmaf(r4[grp][j], r4[grp][j], ss);
        ss += __shfl_xor(ss, 1);
        ss += __shfl_xor(ss, 2);
        const bool is_q = (tid < 64);
        float scale = (is_q ? 0.125f : 1.0f) / sqrtf(ss + 1e-6f);
        float* dst = is_q ? (qn + (size_t)t * KEY_DIM + d0)
                          : (kn + (size_t)t * KEY_DIM + (d0 - KEY_DIM));
        #pragma unroll
        for (int grp = 0; grp < 4; ++grp) {
            fl4 o;
            #pragma unroll
            for (int j = 0; j < 4; ++j) o[j] = r4[grp][j] * scale;
            *(fl4*)(dst + grp * 4) = o;
        }
    } else {
        const int hh = (d0 - 2 * KEY_DIM) >> 6;
        const float bb = sigmoid_f(bsrc[(size_t)t * NVH + hh]);
        float* dst = vb + (size_t)t * VAL_DIM + (d0 - 2 * KEY_DIM);
        #pragma unroll
        for (int grp = 0; grp < 4; ++grp) {
            fl4 o;
            #pragma unroll
            for (int j = 0; j < 4; ++j) o[j] = r4[grp][j] * bb;
            *(fl4*)(dst + grp * 4) = o;
        }
    }

    if (tid < 32) {
        float av = a[(size_t)t * NVH + tid] + dt_bias[tid];
        float sp = fmaxf(av, 0.f) + log1pf(__expf(-fabsf(av)));
        g[(size_t)t * NVH + tid]    = -__expf(A_log[tid]) * sp;
        beta[(size_t)t * NVH + tid] = sigmoid_f(bsrc[(size_t)t * NVH + tid]);
    }
}

// ---------------------------------------------------------------------------
// Kernel 2 (phase 1): per (chunk c, v-head h), fully parallel.  (unchanged)
// ---------------------------------------------------------------------------
__global__ __launch_bounds__(256) void phase1_kernel(
    const float* __restrict__ qn, const float* __restrict__ kn,
    const float* __restrict__ gws, const float* __restrict__ bws,
    float* __restrict__ gam_g, float* __restrict__ bg_g,
    float* __restrict__ KT_g, float* __restrict__ QT_g,
    float* __restrict__ MTt_g, float* __restrict__ SUt_g)
{
    const int bid = blockIdx.x;
    const int c = bid >> 5, h = bid & 31, kh = h >> 1;
    const int tid = threadIdx.x, lane = tid & 63, wv = tid >> 6;

    __shared__ float Ks[64][68], Qs[64][68], Am[64][68], Tm[64][68];
    __shared__ float Gs[64], Dend[64], Bet[64];
    __shared__ float Xs[4][16][17];

    #pragma unroll
    for (int p = 0; p < 4; ++p) {
        int idx = p * 256 + tid;
        int t = idx >> 4, i4 = (idx & 15) * 4;
        *(fl4*)&Ks[t][i4] = *(const fl4*)&kn[(size_t)(c*64+t)*KEY_DIM + kh*64 + i4];
        *(fl4*)&Qs[t][i4] = *(const fl4*)&qn[(size_t)(c*64+t)*KEY_DIM + kh*64 + i4];
    }
    for (int idx = tid; idx < 64*64; idx += 256) {
        int t = idx >> 6, s = idx & 63;
        Tm[t][s] = (t == s) ? 1.f : 0.f;
    }
    if (tid < 64) {
        float gv = gws[(size_t)(c*64+lane)*NVH + h];
        #pragma unroll
        for (int d = 1; d < 64; d <<= 1) {
            float nv = __shfl_up(gv, d);
            if (lane >= d) gv += nv;
        }
        Gs[lane] = gv;
        float g63 = __shfl(gv, 63);
        Dend[lane] = __expf(g63 - gv);
        float bb = bws[(size_t)(c*64+lane)*NVH + h];
        Bet[lane] = bb;
        float ga = __expf(gv);
        gam_g[(size_t)(c*NVH+h)*64 + lane] = ga;
        bg_g[(size_t)(c*NVH+h)*64 + lane]  = ga * bb;
    }
    __syncthreads();

    if ((h & 1) == 0) {
        float* kdst = KT_g + (size_t)(c*NKH + kh)*64*64;
        float* qdst = QT_g + (size_t)(c*NKH + kh)*64*64;
        const int t = lane;
        #pragma unroll
        for (int ii = 0; ii < 16; ++ii) {
            int i = wv*16 + ii;
            kdst[i*64 + t] = Ks[t][i];
            qdst[i*64 + t] = Qs[t][i];
        }
    }

    float accK[16], accQ[16];
    {
        #pragma unroll
        for (int j = 0; j < 16; ++j) { accK[j] = 0.f; accQ[j] = 0.f; }
        const int t = lane, sbase = wv * 16;
        for (int i4 = 0; i4 < 64; i4 += 4) {
            fl4 kt = *(const fl4*)&Ks[t][i4];
            fl4 qt = *(const fl4*)&Qs[t][i4];
            #pragma unroll
            for (int sj = 0; sj < 16; ++sj) {
                fl4 ks = *(const fl4*)&Ks[sbase + sj][i4];
                accK[sj] += kt[0]*ks[0] + kt[1]*ks[1] + kt[2]*ks[2] + kt[3]*ks[3];
                accQ[sj] += qt[0]*ks[0] + qt[1]*ks[1] + qt[2]*ks[2] + qt[3]*ks[3];
            }
        }
    }
    __syncthreads();
    {
        const int t = lane, sbase = wv * 16;
        const float gt = Gs[t], bt = Bet[t];
        #pragma unroll
        for (int sj = 0; sj < 16; ++sj) {
            int s = sbase + sj;
            float e = __expf(gt - Gs[s]);
            Am[t][s] = (s < t)  ? bt * e * accK[sj] : 0.f;
            Qs[t][s] = (s <= t) ? e * accQ[sj] : 0.f;
        }
    }
    __syncthreads();

    if (lane < 16) {
        const int base = wv * 16;
        const int sj = lane, s = base + sj;
        for (int tl = 1; tl < 16; ++tl) {
            int t = base + tl;
            if (sj < tl) {
                float acc = 0.f;
                for (int il = sj; il < tl; ++il)
                    acc += Am[t][base + il] * Tm[base + il][s];
                Tm[t][s] = -acc;
            }
        }
    }
    for (int L = 1; L <= 3; ++L) {
        __syncthreads();
        if (wv < 4 - L) {
            const int J = wv, I = wv + L;
            const int r = lane & 15, cg = lane >> 4;
            float X[4] = {0.f,0.f,0.f,0.f};
            for (int Kb = J; Kb < I; ++Kb) {
                #pragma unroll
                for (int p = 0; p < 16; ++p) {
                    float av = Am[I*16 + r][Kb*16 + p];
                    #pragma unroll
                    for (int mm = 0; mm < 4; ++mm)
                        X[mm] += av * Tm[Kb*16 + p][J*16 + cg + 4*mm];
                }
            }
            #pragma unroll
            for (int mm = 0; mm < 4; ++mm) Xs[wv][r][cg + 4*mm] = X[mm];
            float Y[4] = {0.f,0.f,0.f,0.f};
            #pragma unroll
            for (int p = 0; p < 16; ++p) {
                float td = Tm[I*16 + r][I*16 + p];
                #pragma unroll
                for (int mm = 0; mm < 4; ++mm)
                    Y[mm] += td * Xs[wv][p][cg + 4*mm];
            }
            #pragma unroll
            for (int mm = 0; mm < 4; ++mm)
                Tm[I*16 + r][J*16 + cg + 4*mm] = -Y[mm];
        }
    }
    __syncthreads();

    {
        float acc[16];
        #pragma unroll
        for (int j = 0; j < 16; ++j) acc[j] = 0.f;
        const int t = lane, sbase = wv * 16;
        for (int i4 = 0; i4 < 64; i4 += 4) {
            fl4 mv = *(const fl4*)&Qs[t][i4];
            #pragma unroll
            for (int sj = 0; sj < 16; ++sj) {
                int s = sbase + sj;
                acc[sj] += mv[0]*Tm[i4+0][s] + mv[1]*Tm[i4+1][s]
                         + mv[2]*Tm[i4+2][s] + mv[3]*Tm[i4+3][s];
            }
        }
        float* dst = MTt_g + (size_t)(c*NVH + h)*64*64;
        #pragma unroll
        for (int sj = 0; sj < 16; ++sj)
            dst[(sbase + sj)*64 + t] = acc[sj];
    }
    {
        float acc[16];
        #pragma unroll
        for (int j = 0; j < 16; ++j) acc[j] = 0.f;
        const int d = lane, sbase = wv * 16;
        for (int t = 0; t < 64; ++t) {
            float kd = Ks[t][d] * Dend[t];
            #pragma unroll
            for (int sj = 0; sj < 16; ++sj)
                acc[sj] += kd * Tm[t][sbase + sj];
        }
        float* dst = SUt_g + (size_t)(c*NVH + h)*64*64;
        #pragma unroll
        for (int sj = 0; sj < 16; ++sj)
            dst[(sbase + sj)*64 + d] = acc[sj];
    }
}

// ---------------------------------------------------------------------------
// Kernel 3 (phase 2): sequential over 32 chunks; block = (head, 8-col slice).
// Matrices staged global->reg->LDS one phase ahead (T14 async split); compute
// reads LDS only: matrix ds_read_b32 (t=lane, 2-way free), shared vector via
// v_readlane broadcast (VALU, no LDS port). 4 barriers/chunk.
// Wave roles: mv=wv>>1 (0: P then o+out; 1: O1 then state), y=wv&1: j-quad.
// ---------------------------------------------------------------------------
__global__ __launch_bounds__(256) void phase2_kernel(
    const float* __restrict__ vbp, const float* __restrict__ gam_g,
    const float* __restrict__ bg_g, const float* __restrict__ KT_g,
    const float* __restrict__ QT_g, const float* __restrict__ MTt_g,
    const float* __restrict__ SUt_g, const float* __restrict__ rs0,
    float* __restrict__ out)
{
    const int bid = blockIdx.x;
    const int h = bid & 31, jg = bid >> 5, kh = h >> 1;
    const int tid = threadIdx.x, lane = tid & 63, wv = tid >> 6;
    const int mv = wv >> 1;          // 0: P / o-path, 1: O1 / state-path
    const int jb = (wv & 1) * 4;     // j-quad base within the 8-col slice

    __shared__ float bufA[8192];     // [0..4096)=KT(c), [4096..8192)=QT(c)
    __shared__ float bufB[8192];     // [0..4096)=MTt(c), [4096..8192)=SUt(c)
    __shared__ float s0s[64][12], wshs[64][12], o1s[64][12];

    // init state slice s0s[d][0..7]
    {
        int idx = tid * 2;
        int d = idx >> 3, j = idx & 7;
        s0s[d][j]     = rs0[((size_t)h*64 + d)*64 + jg*8 + j];
        s0s[d][j + 1] = rs0[((size_t)h*64 + d)*64 + jg*8 + j + 1];
    }

    const int base = wv * 1024 + lane * 4;   // staging offset (floats)

    // prologue: issue rA = KT/QT(chunk 0)
    fl4 rA0, rA1, rA2, rA3, rA4, rA5, rA6, rA7;
    {
        const float* kt = KT_g + (size_t)kh * 4096 + base;
        const float* qt = QT_g + (size_t)kh * 4096 + base;
        rA0 = *(const fl4*)(kt);       rA1 = *(const fl4*)(kt + 256);
        rA2 = *(const fl4*)(kt + 512); rA3 = *(const fl4*)(kt + 768);
        rA4 = *(const fl4*)(qt);       rA5 = *(const fl4*)(qt + 256);
        rA6 = *(const fl4*)(qt + 512); rA7 = *(const fl4*)(qt + 768);
    }

    for (int c = 0; c < NCHUNK; ++c) {
        // write rA -> bufA (compiler inserts the vmcnt wait on rA)
        *(fl4*)&bufA[base      ] = rA0; *(fl4*)&bufA[base +  256] = rA1;
        *(fl4*)&bufA[base +  512] = rA2; *(fl4*)&bufA[base +  768] = rA3;
        *(fl4*)&bufA[4096 + base      ] = rA4; *(fl4*)&bufA[4096 + base +  256] = rA5;
        *(fl4*)&bufA[4096 + base +  512] = rA6; *(fl4*)&bufA[4096 + base +  768] = rA7;

        // issue rB = MTt/SUt(c)  (consumed after Phase A)
        fl4 rB0, rB1, rB2, rB3, rB4, rB5, rB6, rB7;
        {
            const float* mt = MTt_g + (size_t)(c*NVH + h)*4096 + base;
            const float* su = SUt_g + (size_t)(c*NVH + h)*4096 + base;
            rB0 = *(const fl4*)(mt);       rB1 = *(const fl4*)(mt + 256);
            rB2 = *(const fl4*)(mt + 512); rB3 = *(const fl4*)(mt + 768);
            rB4 = *(const fl4*)(su);       rB5 = *(const fl4*)(su + 256);
            rB6 = *(const fl4*)(su + 512); rB7 = *(const fl4*)(su + 768);
        }

        // per-chunk scalars (issued early; consumed in finalizes)
        const float* gamc = gam_g + (size_t)(c*NVH + h)*64;
        const float* bgc  = bg_g  + (size_t)(c*NVH + h)*64;
        const float gend = gamc[63];
        fl4 vbv = {0.f, 0.f, 0.f, 0.f};
        float bgl = 0.f, gml = 0.f;
        if (mv == 0) {
            vbv = *(const fl4*)&vbp[(size_t)(c*64 + lane)*VAL_DIM + h*64 + jg*8 + jb];
            bgl = bgc[lane];
        } else {
            gml = gamc[lane];
        }

        __syncthreads();   // bufA visible; s0s stable

        // ---- Phase A: mv0: P[t=lane][jb..jb+3] via KT; mv1: O1 via QT ----
        fl4 sa = *(const fl4*)&s0s[lane][jb];
        float a0 = 0.f, a1 = 0.f, a2 = 0.f, a3 = 0.f;
        {
            const float* mb = &bufA[mv * 4096 + lane];
            #pragma unroll
            for (int i = 0; i < 64; ++i) {
                float m = mb[i * 64];
                a0 = fmaf(m, rdlane(sa[0], i), a0);
                a1 = fmaf(m, rdlane(sa[1], i), a1);
                a2 = fmaf(m, rdlane(sa[2], i), a2);
                a3 = fmaf(m, rdlane(sa[3], i), a3);
            }
        }
        // finalize A
        if (mv == 0) {
            fl4 wv4;
            wv4[0] = vbv[0] - bgl * a0; wv4[1] = vbv[1] - bgl * a1;
            wv4[2] = vbv[2] - bgl * a2; wv4[3] = vbv[3] - bgl * a3;
            *(fl4*)&wshs[lane][jb] = wv4;
        } else {
            fl4 o4;
            o4[0] = gml * a0; o4[1] = gml * a1; o4[2] = gml * a2; o4[3] = gml * a3;
            *(fl4*)&o1s[lane][jb] = o4;
        }
        __syncthreads();   // wshs/o1s visible; bufA reads done

        // write rB -> bufB (vmcnt auto-wait on rB)
        *(fl4*)&bufB[base      ] = rB0; *(fl4*)&bufB[base +  256] = rB1;
        *(fl4*)&bufB[base +  512] = rB2; *(fl4*)&bufB[base +  768] = rB3;
        *(fl4*)&bufB[4096 + base      ] = rB4; *(fl4*)&bufB[4096 + base +  256] = rB5;
        *(fl4*)&bufB[4096 + base +  512] = rB6; *(fl4*)&bufB[4096 + base +  768] = rB7;

        // issue rA = KT/QT(c+1)  (consumed at next chunk top)
        if (c + 1 < NCHUNK) {
            const float* kt = KT_g + (size_t)((c+1)*NKH + kh)*4096 + base;
            const float* qt = QT_g + (size_t)((c+1)*NKH + kh)*4096 + base;
            rA0 = *(const fl4*)(kt);       rA1 = *(const fl4*)(kt + 256);
            rA2 = *(const fl4*)(kt + 512); rA3 = *(const fl4*)(kt + 768);
            rA4 = *(const fl4*)(qt);       rA5 = *(const fl4*)(qt + 256);
            rA6 = *(const fl4*)(qt + 512); rA7 = *(const fl4*)(qt + 768);
        }
        __syncthreads();   // bufB visible

        // ---- Phase B: mv0: o via MTt; mv1: state-update via SUt ----
        fl4 sb = *(const fl4*)&wshs[lane][jb];
        float b0 = 0.f, b1 = 0.f, b2 = 0.f, b3 = 0.f;
        {
            const float* mb = &bufB[mv * 4096 + lane];
            #pragma unroll
            for (int i = 0; i < 64; ++i) {
                float m = mb[i * 64];
                b0 = fmaf(m, rdlane(sb[0], i), b0);
                b1 = fmaf(m, rdlane(sb[1], i), b1);
                b2 = fmaf(m, rdlane(sb[2], i), b2);
                b3 = fmaf(m, rdlane(sb[3], i), b3);
            }
        }
        // finalize B
        if (mv == 0) {
            fl4 o1v = *(const fl4*)&o1s[lane][jb];
            fl4 ov;
            ov[0] = o1v[0] + b0; ov[1] = o1v[1] + b1;
            ov[2] = o1v[2] + b2; ov[3] = o1v[3] + b3;
            *(fl4*)&out[(size_t)(c*64 + lane)*VAL_DIM + h*64 + jg*8 + jb] = ov;
        } else {
            fl4 sv = *(const fl4*)&s0s[lane][jb];
            fl4 nv;
            nv[0] = gend * sv[0] + b0; nv[1] = gend * sv[1] + b1;
            nv[2] = gend * sv[2] + b2; nv[3] = gend * sv[3] + b3;
            *(fl4*)&s0s[lane][jb] = nv;
        }
        __syncthreads();   // s0s updated for next chunk
    }
}

// ---------------------------------------------------------------------------
// Fallback: sequential scan (only if ws too small). Uses vb (=beta*v).
// ---------------------------------------------------------------------------
#define LOADSTEP(KA, QA, VV, GG, BB, tt) {                                     \
    _Pragma("unroll")                                                          \
    for (int i = 0; i < 4; ++i) {                                              \
        KA[i] = *(const fl4*)(kp + (size_t)(tt) * KEY_DIM + i * 4);            \
        QA[i] = *(const fl4*)(qp + (size_t)(tt) * KEY_DIM + i * 4);            \
    }                                                                          \
    VV = vp[(size_t)(tt) * VAL_DIM];                                           \
    GG = gp[(size_t)(tt) * NVH];                                               \
    BB = bp[(size_t)(tt) * NVH];                                               \
}

#define COMPUTE(KA, QA, VV, GG, BB, tt) {                                      \
    const float dec = __expf(GG);                                              \
    float c0 = 0.f, c1 = 0.f, c2 = 0.f, c3 = 0.f;                              \
    _Pragma("unroll")                                                          \
    for (int i = 0; i < 4; ++i) {                                              \
        S[i*4+0] *= dec; S[i*4+1] *= dec; S[i*4+2] *= dec; S[i*4+3] *= dec;    \
        c0 = fmaf(S[i*4+0], KA[i][0], c0);                                     \
        c1 = fmaf(S[i*4+1], KA[i][1], c1);                                     \
        c2 = fmaf(S[i*4+2], KA[i][2], c2);                                     \
        c3 = fmaf(S[i*4+3], KA[i][3], c3);                                     \
    }                                                                          \
    float kv = (c0 + c1) + (c2 + c3);                                          \
    kv += __shfl_xor(kv, 1);                                                   \
    kv += __shfl_xor(kv, 2);                                                   \
    const float u = VV - BB * kv;                                              \
    float o0 = 0.f, o1 = 0.f, o2 = 0.f, o3 = 0.f;                              \
    _Pragma("unroll")                                                          \
    for (int i = 0; i < 4; ++i) {                                              \
        S[i*4+0] = fmaf(KA[i][0], u, S[i*4+0]);                                \
        S[i*4+1] = fmaf(KA[i][1], u, S[i*4+1]);                                \
        S[i*4+2] = fmaf(KA[i][2], u, S[i*4+2]);                                \
        S[i*4+3] = fmaf(KA[i][3], u, S[i*4+3]);                                \
        o0 = fmaf(S[i*4+0], QA[i][0], o0);                                     \
        o1 = fmaf(S[i*4+1], QA[i][1], o1);                                     \
        o2 = fmaf(S[i*4+2], QA[i][2], o2);                                     \
        o3 = fmaf(S[i*4+3], QA[i][3], o3);                                     \
    }                                                                          \
    float oo = (o0 + o1) + (o2 + o3);                                          \
    oo += __shfl_xor(oo, 1);                                                   \
    oo += __shfl_xor(oo, 2);                                                   \
    if (kg == 0) op[(size_t)(tt) * VAL_DIM] = oo;                              \
}

__global__ __launch_bounds__(256) void scan_kernel(
    const float* __restrict__ qn, const float* __restrict__ kn,
    const float* __restrict__ v, const float* __restrict__ g,
    const float* __restrict__ bet, const float* __restrict__ rs0,
    float* __restrict__ out)
{
    const int h    = blockIdx.x;
    const int kh   = h >> 1;
    const int tid  = threadIdx.x;
    const int vcol = tid >> 2;
    const int kg   = tid & 3;

    float S[16];
    #pragma unroll
    for (int j = 0; j < 16; ++j)
        S[j] = rs0[((size_t)h * HD + (kg * 16 + j)) * HD + vcol];

    const float* kp = kn + (size_t)kh * HD + kg * 16;
    const float* qp = qn + (size_t)kh * HD + kg * 16;
    const float* vp = v + (size_t)h * HD + vcol;
    const float* gp = g + h;
    const float* bp = bet + h;
    float*       op = out + (size_t)h * HD + vcol;

    fl4 ka0[4], qa0[4]; float vv0, gg0, bb0;
    fl4 ka1[4], qa1[4]; float vv1, gg1, bb1;

    LOADSTEP(ka0, qa0, vv0, gg0, bb0, 0);
    for (int t = 0; t < T_LEN; t += 2) {
        LOADSTEP(ka1, qa1, vv1, gg1, bb1, t + 1);
        COMPUTE(ka0, qa0, vv0, gg0, bb0, t);
        const int t2 = (t + 2 < T_LEN) ? (t + 2) : (T_LEN - 1);
        LOADSTEP(ka0, qa0, vv0, gg0, bb0, t2);
        COMPUTE(ka1, qa1, vv1, gg1, bb1, t + 1);
    }
}

// ---------------------------------------------------------------------------
extern "C" void kernel_launch(void* const* d_in, const int* in_sizes, int n_in,
                              void* d_out, int out_size, void* d_ws, size_t ws_size,
                              hipStream_t stream)
{
    const float* x       = (const float*)d_in[0];
    const float* cs      = (const float*)d_in[1];
    const float* rs0     = (const float*)d_in[2];
    const float* b       = (const float*)d_in[3];
    const float* a       = (const float*)d_in[4];
    const float* w       = (const float*)d_in[5];
    const float* A_log   = (const float*)d_in[6];
    const float* dt_bias = (const float*)d_in[7];
    float* out = (float*)d_out;

    float* ws = (float*)d_ws;
    size_t off = 0;
    float* qn  = ws + off; off += (size_t)T_LEN * KEY_DIM;
    float* kn  = ws + off; off += (size_t)T_LEN * KEY_DIM;
    float* vb  = ws + off; off += (size_t)T_LEN * VAL_DIM;
    float* g   = ws + off; off += (size_t)T_LEN * NVH;
    float* be  = ws + off; off += (size_t)T_LEN * NVH;
    float* gam = ws + off; off += (size_t)NCHUNK * NVH * 64;
    float* bg  = ws + off; off += (size_t)NCHUNK * NVH * 64;
    float* KT  = ws + off; off += (size_t)NCHUNK * NKH * 64 * 64;
    float* QT  = ws + off; off += (size_t)NCHUNK * NKH * 64 * 64;
    float* MTt = ws + off; off += (size_t)NCHUNK * NVH * 64 * 64;
    float* SUt = ws + off; off += (size_t)NCHUNK * NVH * 64 * 64;
    const size_t need = off * sizeof(float);

    prep_kernel<<<T_LEN, 256, 0, stream>>>(x, cs, w, b, a, A_log, dt_bias,
                                           qn, kn, vb, g, be);
    if (ws_size >= need) {
        phase1_kernel<<<NCHUNK * NVH, 256, 0, stream>>>(qn, kn, g, be,
                                                        gam, bg, KT, QT, MTt, SUt);
        phase2_kernel<<<NVH * 8, 256, 0, stream>>>(vb, gam, bg, KT, QT, MTt, SUt,
                                                   rs0, out);
    } else {
        scan_kernel<<<NVH, 256, 0, stream>>>(qn, kn, vb, g, be, rs0, out);
    }
}